// Round 2
// baseline (200.683 us; speedup 1.0000x reference)
//
#include <hip/hip_runtime.h>
#include <math.h>

#define NNODES 16384
#define NV 16385
#define NEDGE 131072
#define NEG -1e30f

// Scratch as static device globals (fully rewritten every launch).
__device__ float g_AB[NV * 512];     // [v][0:256]=A=emb@W1_top, [256:512]=B=emb@W1_bot
__device__ float g_d[NEDGE];         // edge distances
__device__ float g_mats[256 * 64];   // 256 chunk matrices (8x8, row-major)
__device__ float g_mats2[16 * 64];   // level-2 combined matrices

__device__ __forceinline__ float lse8(float x0, float x1, float x2, float x3,
                                      float x4, float x5, float x6, float x7) {
  float m = fmaxf(fmaxf(fmaxf(x0, x1), fmaxf(x2, x3)),
                  fmaxf(fmaxf(x4, x5), fmaxf(x6, x7)));
  float s = __expf(x0 - m) + __expf(x1 - m) + __expf(x2 - m) + __expf(x3 - m) +
            __expf(x4 - m) + __expf(x5 - m) + __expf(x6 - m) + __expf(x7 - m);
  return m + __logf(s);
}

// K1: AB[v][h2] = emb[v] @ [W1_top | W1_bot]   (M=16385, K=128, N=512) fp32
__global__ __launch_bounds__(256) void k1_gemm(const float* __restrict__ emb,
                                               const float* __restrict__ W1) {
  __shared__ float As[128][64];  // As[k][m] (transposed emb tile)
  __shared__ float Bs[128][64];  // Bs[k][n]
  const int t = threadIdx.x;
  const int v0 = blockIdx.x << 6;
  const int h0 = blockIdx.y << 6;  // 0..448
  const int roff = (h0 < 256) ? 0 : 128;
  const int c0 = (h0 < 256) ? h0 : (h0 - 256);
#pragma unroll
  for (int it = 0; it < 8; ++it) {
    int idx = t + (it << 8);       // float4 idx, 2048 total
    int row = idx >> 5;            // 0..63
    int k0 = (idx & 31) << 2;
    float4 g = make_float4(0.f, 0.f, 0.f, 0.f);
    int v = v0 + row;
    if (v < NV) g = *(const float4*)&emb[v * 128 + k0];
    As[k0 + 0][row] = g.x;
    As[k0 + 1][row] = g.y;
    As[k0 + 2][row] = g.z;
    As[k0 + 3][row] = g.w;
  }
#pragma unroll
  for (int it = 0; it < 8; ++it) {
    int idx = t + (it << 8);
    int row = idx >> 4;            // 0..127
    int n0 = (idx & 15) << 2;
    *(float4*)&Bs[row][n0] = *(const float4*)&W1[(roff + row) * 256 + c0 + n0];
  }
  __syncthreads();
  const int tx = t & 15, ty = t >> 4;
  const int m0 = ty << 2, n0 = tx << 2;
  float acc[4][4];
#pragma unroll
  for (int a = 0; a < 4; ++a)
#pragma unroll
    for (int b = 0; b < 4; ++b) acc[a][b] = 0.f;
#pragma unroll 4
  for (int k = 0; k < 128; ++k) {
    float4 a4 = *(const float4*)&As[k][m0];
    float4 b4 = *(const float4*)&Bs[k][n0];
    float av[4] = {a4.x, a4.y, a4.z, a4.w};
    float bv[4] = {b4.x, b4.y, b4.z, b4.w};
#pragma unroll
    for (int a = 0; a < 4; ++a)
#pragma unroll
      for (int b = 0; b < 4; ++b) acc[a][b] = fmaf(av[a], bv[b], acc[a][b]);
  }
#pragma unroll
  for (int a = 0; a < 4; ++a) {
    int v = v0 + m0 + a;
    if (v < NV)
      *(float4*)&g_AB[v * 512 + h0 + n0] =
          make_float4(acc[a][0], acc[a][1], acc[a][2], acc[a][3]);
  }
}

// K2: per-edge distance. One wave per edge (64 lanes x 4 h each), 32 edges/wave.
__global__ __launch_bounds__(256) void k2_dist(const float* __restrict__ b1,
                                               const float* __restrict__ W2,
                                               const float* __restrict__ b2) {
  const int lane = threadIdx.x & 63;
  const int wid = blockIdx.x * 4 + (threadIdx.x >> 6);
  const float b2v = b2[0];
  float b1v[4], w2v[4];
#pragma unroll
  for (int j = 0; j < 4; ++j) {
    b1v[j] = b1[lane + (j << 6)];
    w2v[j] = W2[lane + (j << 6)];
  }
  const int e0 = wid << 5;
  for (int ee = 0; ee < 32; ++ee) {
    const int e = e0 + ee;
    const int irow = e >> 3;  // i-1
    int p = irow - (e & 7);
    p = p < 0 ? 0 : p;  // matches reference's clamped pred_nodes (masked later)
    const float* __restrict__ Ap = &g_AB[p * 512];
    const float* __restrict__ Bi = &g_AB[(irow + 1) * 512 + 256];
    float acc = 0.f;
#pragma unroll
    for (int j = 0; j < 4; ++j) {
      const int h = lane + (j << 6);
      float x = Ap[h] + Bi[h] + b1v[j];
      float ex = __expf(x + x);
      float th = 1.f - 2.f / (ex + 1.f);  // tanh(x)
      acc = fmaf(th, w2v[j], acc);
    }
#pragma unroll
    for (int off = 32; off > 0; off >>= 1) acc += __shfl_xor(acc, off, 64);
    if (lane == 0) {
      const float tv = acc + b2v;
      g_d[e] = fmaxf(tv, 0.f) + __logf(1.f + __expf(-fabsf(tv)));  // softplus
    }
  }
}

// K3: 256 chunks of L=64 steps; each 8-lane group owns one chunk, lane j owns
// column j of the running 8x8 log-semiring product. 8 blocks x 4 waves x 8 chunks.
__global__ __launch_bounds__(256) void k3_chunks() {
  __shared__ float w[4][64][64];  // [wave][step][g*8+k] = d value, 64 KB
  const int t = threadIdx.x;
  const int b = blockIdx.x;  // 0..7
  const float* __restrict__ src = &g_d[b << 14];
#pragma unroll
  for (int it = 0; it < 16; ++it) {
    const int q4 = t + (it << 8);
    const int q = q4 << 2;
    const int cl = q >> 9;  // chunk-local 0..31
    const int wv = cl >> 3, g = cl & 7;
    const int r = q & 511;
    const int s = r >> 3, k = r & 7;
    *(float4*)&w[wv][s][(g << 3) + k] = *(const float4*)&src[q];
  }
  __syncthreads();
  if (b == 0 && t == 0) {
    // node i = s+1 has valid preds k <= s only: poison invalid d with +1e30
    for (int s = 0; s < 7; ++s)
      for (int k = s + 1; k < 8; ++k) w[0][s][k] = 1e30f;
  }
  __syncthreads();
  const int wave = t >> 6, lane = t & 63;
  const int g = lane >> 3, j = lane & 7;
  float P[8];
#pragma unroll
  for (int k = 0; k < 8; ++k) P[k] = (k == j) ? 0.f : NEG;
  for (int s = 0; s < 64; ++s) {
    const float* wp = &w[wave][s][g << 3];
    float4 wa = *(const float4*)wp;
    float4 wb = *(const float4*)(wp + 4);
    float nv = lse8(P[0] - wa.x, P[1] - wa.y, P[2] - wa.z, P[3] - wa.w,
                    P[4] - wb.x, P[5] - wb.y, P[6] - wb.z, P[7] - wb.w);
#pragma unroll
    for (int k = 7; k > 0; --k) P[k] = P[k - 1];
    P[0] = nv;
  }
  const int c = (b << 5) + (wave << 3) + g;
  float* mp = &g_mats[(c << 6) + j];
#pragma unroll
  for (int k = 0; k < 8; ++k) mp[k << 3] = P[k];
}

// K4: 16 blocks, each combines 16 consecutive chunk matrices sequentially.
// (A (X) B)[i][j] = lse_k(A[i][k] + B[k][j]), A = later chunk.
__global__ __launch_bounds__(64) void k4_comb() {
  __shared__ float Bm[64];
  const int l = threadIdx.x;
  const int r = blockIdx.x;  // 0..15
  const int i = l >> 3, j = l & 7;
  Bm[l] = g_mats[(r << 10) + l];
  __syncthreads();
  for (int tt = 1; tt < 16; ++tt) {
    const float* __restrict__ A = &g_mats[(((r << 4) + tt) << 6) + (i << 3)];
    float nv = lse8(A[0] + Bm[j], A[1] + Bm[8 + j], A[2] + Bm[16 + j],
                    A[3] + Bm[24 + j], A[4] + Bm[32 + j], A[5] + Bm[40 + j],
                    A[6] + Bm[48 + j], A[7] + Bm[56 + j]);
    __syncthreads();
    Bm[(i << 3) + j] = nv;
    __syncthreads();
  }
  g_mats2[(r << 6) + l] = Bm[l];
}

// K5: gold-path reduction + final combine of 16 matrices + output.
__global__ __launch_bounds__(256) void k5_final(float* __restrict__ out) {
  __shared__ float red[256];
  __shared__ float Bm[64];
  const int t = threadIdx.x;
  float s = 0.f;
#pragma unroll
  for (int rr = 0; rr < 64; ++rr) s += g_d[(t + (rr << 8)) << 3];  // k=0 edges
  red[t] = s;
  __syncthreads();
  for (int o = 128; o > 0; o >>= 1) {
    if (t < o) red[t] += red[t + o];
    __syncthreads();
  }
  if (t < 64) Bm[t] = g_mats2[t];
  __syncthreads();
  const int i = t >> 3, j = t & 7;
  for (int tt = 1; tt < 16; ++tt) {
    float nv = 0.f;
    if (t < 64) {
      const float* __restrict__ A = &g_mats2[(tt << 6) + (i << 3)];
      nv = lse8(A[0] + Bm[j], A[1] + Bm[8 + j], A[2] + Bm[16 + j],
                A[3] + Bm[24 + j], A[4] + Bm[32 + j], A[5] + Bm[40 + j],
                A[6] + Bm[48 + j], A[7] + Bm[56 + j]);
    }
    __syncthreads();
    if (t < 64) Bm[(i << 3) + j] = nv;
    __syncthreads();
  }
  if (t == 0) out[0] = red[0] + Bm[0];  // gold + fwd = gold + (prod)[0][0]
}

extern "C" void kernel_launch(void* const* d_in, const int* in_sizes, int n_in,
                              void* d_out, int out_size, void* d_ws, size_t ws_size,
                              hipStream_t stream) {
  const float* emb = (const float*)d_in[0];
  const float* W1 = (const float*)d_in[1];
  const float* b1 = (const float*)d_in[2];
  const float* W2 = (const float*)d_in[3];
  const float* b2 = (const float*)d_in[4];
  float* out = (float*)d_out;
  hipLaunchKernelGGL(k1_gemm, dim3(257, 8), dim3(256), 0, stream, emb, W1);
  hipLaunchKernelGGL(k2_dist, dim3(1024), dim3(256), 0, stream, b1, W2, b2);
  hipLaunchKernelGGL(k3_chunks, dim3(8), dim3(256), 0, stream);
  hipLaunchKernelGGL(k4_comb, dim3(16), dim3(64), 0, stream);
  hipLaunchKernelGGL(k5_final, dim3(1), dim3(256), 0, stream, out);
}

// Round 3
// 195.318 us; speedup vs baseline: 1.0275x; 1.0275x over previous
//
#include <hip/hip_runtime.h>
#include <math.h>

#define NNODES 16384
#define NV 16385
#define NEDGE 131072
#define NEG -1e30f

typedef __attribute__((ext_vector_type(8))) short short8;
typedef __attribute__((ext_vector_type(4))) float f32x4;

// Scratch as static device globals (fully rewritten every launch).
__device__ unsigned short g_AB[NV * 512];  // bf16: [v][0:256]=A=emb@W1_top, [256:512]=B=emb@W1_bot
__device__ float g_d[NEDGE];               // edge distances
__device__ float g_mats[256 * 64];         // 256 chunk matrices (8x8, row-major)
__device__ float g_mats2[16 * 64];         // level-2 combined matrices
__device__ float g_gold;                   // gold-path sum (zeroed in k1)

__device__ __forceinline__ unsigned short f2bf(float x) {
  union { float f; unsigned int u; } c; c.f = x;
  unsigned int u = c.u;
  unsigned int r = (u + 0x7fffu + ((u >> 16) & 1u)) >> 16;  // RNE
  return (unsigned short)r;
}
__device__ __forceinline__ float bf2f(unsigned short u) {
  union { unsigned int u; float f; } c; c.u = ((unsigned int)u) << 16;
  return c.f;
}

__device__ __forceinline__ float lse8(float x0, float x1, float x2, float x3,
                                      float x4, float x5, float x6, float x7) {
  float m = fmaxf(fmaxf(fmaxf(x0, x1), fmaxf(x2, x3)),
                  fmaxf(fmaxf(x4, x5), fmaxf(x6, x7)));
  float s = __expf(x0 - m) + __expf(x1 - m) + __expf(x2 - m) + __expf(x3 - m) +
            __expf(x4 - m) + __expf(x5 - m) + __expf(x6 - m) + __expf(x7 - m);
  return m + __logf(s);
}

// K1: AB[v][h2] = emb[v] @ [W1_top | W1_bot]  (M=16385, K=128, N=512), bf16 MFMA.
// Tile: 128 (M) x 64 (N), full K=128 staged once. Grid (8 N-tiles, 129 M-tiles).
__global__ __launch_bounds__(256) void k1_gemm(const float* __restrict__ emb,
                                               const float* __restrict__ W1) {
  __shared__ unsigned short Alds[128][136];  // [m][k], +8 pad breaks 16-way conflicts
  __shared__ unsigned short Blds[64][136];   // [n][k]
  const int t = threadIdx.x;
  const int h0 = blockIdx.x << 6;   // N-tile: 0..448
  const int v0 = blockIdx.y << 7;   // M-tile * 128
  const int roff = (h0 < 256) ? 0 : 128;
  const int c0 = (h0 < 256) ? h0 : (h0 - 256);
  if (blockIdx.x == 0 && blockIdx.y == 0 && t == 0) g_gold = 0.f;

  // Stage A: 128 rows x 128 k, fp32 -> bf16.
#pragma unroll
  for (int it = 0; it < 16; ++it) {
    int idx = t + (it << 8);        // 0..4095 float4 units
    int row = idx >> 5;             // 0..127
    int k4 = (idx & 31) << 2;
    float4 g = make_float4(0.f, 0.f, 0.f, 0.f);
    int v = v0 + row;
    if (v < NV) g = *(const float4*)&emb[v * 128 + k4];
    unsigned int p0 = f2bf(g.x) | ((unsigned int)f2bf(g.y) << 16);
    unsigned int p1 = f2bf(g.z) | ((unsigned int)f2bf(g.w) << 16);
    *(unsigned int*)&Alds[row][k4] = p0;
    *(unsigned int*)&Alds[row][k4 + 2] = p1;
  }
  // Stage B transposed: Blds[n][k] = W1[roff+k][c0+n].
  {
    const int n = t & 63;
    const int kb = (t >> 6) << 5;   // 0,32,64,96
#pragma unroll
    for (int kk = 0; kk < 32; kk += 2) {
      int k = kb + kk;
      float w0 = W1[(roff + k) * 256 + c0 + n];
      float w1 = W1[(roff + k + 1) * 256 + c0 + n];
      *(unsigned int*)&Blds[n][k] = f2bf(w0) | ((unsigned int)f2bf(w1) << 16);
    }
  }
  __syncthreads();

  const int wave = t >> 6, lane = t & 63;
  const int lrow = lane & 15;
  const int kq = (lane >> 4) << 3;  // 0,8,16,24
  f32x4 acc[2][4];
#pragma unroll
  for (int a = 0; a < 2; ++a)
#pragma unroll
    for (int b = 0; b < 4; ++b) acc[a][b] = (f32x4){0.f, 0.f, 0.f, 0.f};

#pragma unroll
  for (int kc = 0; kc < 4; ++kc) {
    const int kbase = (kc << 5) + kq;
    short8 a0 = *(const short8*)&Alds[(wave << 5) + lrow][kbase];
    short8 a1 = *(const short8*)&Alds[(wave << 5) + 16 + lrow][kbase];
#pragma unroll
    for (int nf = 0; nf < 4; ++nf) {
      short8 b = *(const short8*)&Blds[(nf << 4) + lrow][kbase];
      acc[0][nf] = __builtin_amdgcn_mfma_f32_16x16x32_bf16(a0, b, acc[0][nf], 0, 0, 0);
      acc[1][nf] = __builtin_amdgcn_mfma_f32_16x16x32_bf16(a1, b, acc[1][nf], 0, 0, 0);
    }
  }
  // Store: D row = quad*4+reg, col = lane&15 (m89-verified layout).
#pragma unroll
  for (int mf = 0; mf < 2; ++mf) {
    const int mrow = v0 + (wave << 5) + (mf << 4) + ((lane >> 4) << 2);
#pragma unroll
    for (int nf = 0; nf < 4; ++nf) {
      const int col = h0 + (nf << 4) + lrow;
      f32x4 a = acc[mf][nf];
#pragma unroll
      for (int r = 0; r < 4; ++r) {
        int v = mrow + r;
        if (v < NV) g_AB[v * 512 + col] = f2bf(a[r]);
      }
    }
  }
}

// K2: per-edge distance. One wave per edge (64 lanes x 4 contiguous h), 32 edges/wave.
// Also accumulates gold-path sum (edges with k==0) via one atomicAdd per wave.
__global__ __launch_bounds__(256) void k2_dist(const float* __restrict__ b1,
                                               const float* __restrict__ W2,
                                               const float* __restrict__ b2) {
  const int lane = threadIdx.x & 63;
  const int wid = blockIdx.x * 4 + (threadIdx.x >> 6);
  const float b2v = b2[0];
  const float4 b1v = *(const float4*)&b1[lane << 2];
  const float4 w2v = *(const float4*)&W2[lane << 2];
  const int e0 = wid << 5;
  float gold = 0.f;
  for (int ee = 0; ee < 32; ++ee) {
    const int e = e0 + ee;
    const int irow = e >> 3;  // i-1
    int p = irow - (e & 7);
    p = p < 0 ? 0 : p;
    ushort4 au = *(const ushort4*)&g_AB[p * 512 + (lane << 2)];
    ushort4 bu = *(const ushort4*)&g_AB[(irow + 1) * 512 + 256 + (lane << 2)];
    float x0 = bf2f(au.x) + bf2f(bu.x) + b1v.x;
    float x1 = bf2f(au.y) + bf2f(bu.y) + b1v.y;
    float x2 = bf2f(au.z) + bf2f(bu.z) + b1v.z;
    float x3 = bf2f(au.w) + bf2f(bu.w) + b1v.w;
    float t0 = 1.f - 2.f / (__expf(x0 + x0) + 1.f);
    float t1 = 1.f - 2.f / (__expf(x1 + x1) + 1.f);
    float t2 = 1.f - 2.f / (__expf(x2 + x2) + 1.f);
    float t3 = 1.f - 2.f / (__expf(x3 + x3) + 1.f);
    float acc = t0 * w2v.x + t1 * w2v.y + t2 * w2v.z + t3 * w2v.w;
#pragma unroll
    for (int off = 32; off > 0; off >>= 1) acc += __shfl_xor(acc, off, 64);
    if (lane == 0) {
      const float tv = acc + b2v;
      const float dd = fmaxf(tv, 0.f) + __logf(1.f + __expf(-fabsf(tv)));
      g_d[e] = dd;
      if ((e & 7) == 0) gold += dd;
    }
  }
  if (lane == 0) atomicAdd(&g_gold, gold);
}

// K3: 256 chunks of L=64 steps; 32 blocks x 64 threads, 8 chunks/block.
// Each 8-lane group owns one chunk; lane j owns column j of the 8x8 product.
__global__ __launch_bounds__(64) void k3_chunks() {
  __shared__ float w[64][64];  // [step][chunk_local*8 + k]
  const int t = threadIdx.x;
  const int b = blockIdx.x;  // 0..31
  const float* __restrict__ src = &g_d[b << 12];
#pragma unroll
  for (int it = 0; it < 16; ++it) {
    const int q = (t + (it << 6)) << 2;  // 0..4095 in steps of 4
    const int cl = q >> 9;               // chunk-local 0..7
    const int r = q & 511;
    const int s = r >> 3, k = r & 7;
    *(float4*)&w[s][(cl << 3) + k] = *(const float4*)&src[q];
  }
  __syncthreads();
  if (b == 0 && t == 0) {
    // node i = s+1 has valid preds k <= s only: poison invalid d with +1e30
    for (int s = 0; s < 7; ++s)
      for (int k = s + 1; k < 8; ++k) w[s][k] = 1e30f;
  }
  __syncthreads();
  const int g = t >> 3, j = t & 7;
  float P[8];
#pragma unroll
  for (int k = 0; k < 8; ++k) P[k] = (k == j) ? 0.f : NEG;
  for (int s = 0; s < 64; ++s) {
    const float* wp = &w[s][g << 3];
    float4 wa = *(const float4*)wp;
    float4 wb = *(const float4*)(wp + 4);
    float nv = lse8(P[0] - wa.x, P[1] - wa.y, P[2] - wa.z, P[3] - wa.w,
                    P[4] - wb.x, P[5] - wb.y, P[6] - wb.z, P[7] - wb.w);
#pragma unroll
    for (int k = 7; k > 0; --k) P[k] = P[k - 1];
    P[0] = nv;
  }
  const int c = (b << 3) + g;
  float* mp = &g_mats[(c << 6) + j];
#pragma unroll
  for (int k = 0; k < 8; ++k) mp[k << 3] = P[k];
}

// K4: 16 blocks, each combines 16 consecutive chunk matrices sequentially.
__global__ __launch_bounds__(64) void k4_comb() {
  __shared__ float Bm[64];
  const int l = threadIdx.x;
  const int r = blockIdx.x;  // 0..15
  const int i = l >> 3, j = l & 7;
  Bm[l] = g_mats[(r << 10) + l];
  __syncthreads();
  for (int tt = 1; tt < 16; ++tt) {
    const float* __restrict__ A = &g_mats[(((r << 4) + tt) << 6) + (i << 3)];
    float nv = lse8(A[0] + Bm[j], A[1] + Bm[8 + j], A[2] + Bm[16 + j],
                    A[3] + Bm[24 + j], A[4] + Bm[32 + j], A[5] + Bm[40 + j],
                    A[6] + Bm[48 + j], A[7] + Bm[56 + j]);
    __syncthreads();
    Bm[(i << 3) + j] = nv;
    __syncthreads();
  }
  g_mats2[(r << 6) + l] = Bm[l];
}

// K5: final combine of 16 matrices + gold + output.
__global__ __launch_bounds__(64) void k5_final(float* __restrict__ out) {
  __shared__ float Bm[64];
  const int t = threadIdx.x;
  Bm[t] = g_mats2[t];
  __syncthreads();
  const int i = t >> 3, j = t & 7;
  for (int tt = 1; tt < 16; ++tt) {
    const float* __restrict__ A = &g_mats2[(tt << 6) + (i << 3)];
    float nv = lse8(A[0] + Bm[j], A[1] + Bm[8 + j], A[2] + Bm[16 + j],
                    A[3] + Bm[24 + j], A[4] + Bm[32 + j], A[5] + Bm[40 + j],
                    A[6] + Bm[48 + j], A[7] + Bm[56 + j]);
    __syncthreads();
    Bm[(i << 3) + j] = nv;
    __syncthreads();
  }
  if (t == 0) out[0] = g_gold + Bm[0];
}

extern "C" void kernel_launch(void* const* d_in, const int* in_sizes, int n_in,
                              void* d_out, int out_size, void* d_ws, size_t ws_size,
                              hipStream_t stream) {
  const float* emb = (const float*)d_in[0];
  const float* W1 = (const float*)d_in[1];
  const float* b1 = (const float*)d_in[2];
  const float* W2 = (const float*)d_in[3];
  const float* b2 = (const float*)d_in[4];
  float* out = (float*)d_out;
  hipLaunchKernelGGL(k1_gemm, dim3(8, 129), dim3(256), 0, stream, emb, W1);
  hipLaunchKernelGGL(k2_dist, dim3(1024), dim3(256), 0, stream, b1, W2, b2);
  hipLaunchKernelGGL(k3_chunks, dim3(32), dim3(64), 0, stream);
  hipLaunchKernelGGL(k4_comb, dim3(16), dim3(64), 0, stream);
  hipLaunchKernelGGL(k5_final, dim3(1), dim3(64), 0, stream, out);
}

// Round 4
// 142.378 us; speedup vs baseline: 1.4095x; 1.3718x over previous
//
#include <hip/hip_runtime.h>
#include <math.h>

#define NNODES 16384
#define NV 16385
#define NEDGE 131072
#define NEG -1e30f

typedef __attribute__((ext_vector_type(8))) short short8;
typedef __attribute__((ext_vector_type(8))) unsigned short ushort8;
typedef __attribute__((ext_vector_type(4))) float f32x4;

// Scratch as static device globals (fully rewritten every launch).
__device__ float g_part[4 * NEDGE];  // per-h-tile partial edge sums
__device__ float g_d[NEDGE];         // edge distances
__device__ float g_mats[256 * 64];   // 256 chunk matrices (8x8, row-major)
__device__ float g_mats2[16 * 64];   // level-2 combined matrices
__device__ float g_gold;             // gold-path sum

__device__ __forceinline__ unsigned short f2bf(float x) {
  union { float f; unsigned int u; } c; c.f = x;
  unsigned int u = c.u;
  unsigned int r = (u + 0x7fffu + ((u >> 16) & 1u)) >> 16;  // RNE
  return (unsigned short)r;
}
__device__ __forceinline__ float bf2f(unsigned short u) {
  union { unsigned int u; float f; } c; c.u = ((unsigned int)u) << 16;
  return c.f;
}

__device__ __forceinline__ float lse8(float x0, float x1, float x2, float x3,
                                      float x4, float x5, float x6, float x7) {
  float m = fmaxf(fmaxf(fmaxf(x0, x1), fmaxf(x2, x3)),
                  fmaxf(fmaxf(x4, x5), fmaxf(x6, x7)));
  float s = __expf(x0 - m) + __expf(x1 - m) + __expf(x2 - m) + __expf(x3 - m) +
            __expf(x4 - m) + __expf(x5 - m) + __expf(x6 - m) + __expf(x7 - m);
  return m + __logf(s);
}

// Fused projection + edge kernel. Grid (4 h-tiles, 128 node-tiles), 256 thr.
// Block (hx, vy): h in [hx*64, hx*64+64), nodes i in [i0+1, i0+128], i0=vy*128.
// Phase 1: MFMA  A[p][h]=emb[p]@W1_top  (Es rows 0..134 <-> p=i0-7+r),
//                B[i][h]=emb[i]@W1_bot  (rows q <-> i=i0+1+q).
// Phase 2: per-edge partial: sum_h tanh(A+B+b1)*W2 -> g_part[hx][e].
__global__ __launch_bounds__(256) void k12_fused(const float* __restrict__ emb,
                                                 const float* __restrict__ W1,
                                                 const float* __restrict__ b1,
                                                 const float* __restrict__ W2) {
  __shared__ unsigned short lds[19648];        // 39.3 KB
  unsigned short* Es  = lds;                   // [144][72] (pitch 72, 4-bank shift)
  unsigned short* WtA = lds + 10368;           // [64][72]
  unsigned short* WtB = lds + 14976;           // [64][72]
  unsigned short* CA  = lds;                   // [135][72]  (aliases Es, phase 2)
  unsigned short* CB  = lds + 10368;           // [128][72]
  unsigned short* W2s = lds + 19584;           // [64]

  const int t = threadIdx.x;
  const int h0 = blockIdx.x << 6;
  const int i0 = blockIdx.y << 7;
  if (blockIdx.x == 0 && blockIdx.y == 0 && t == 0) g_gold = 0.f;
  const int wv = t >> 6, lane = t & 63;
  const int l15 = lane & 15, quad = lane >> 4;

  f32x4 accA[9], accB[8];
#pragma unroll
  for (int m = 0; m < 9; ++m) accA[m] = (f32x4){0.f, 0.f, 0.f, 0.f};
#pragma unroll
  for (int m = 0; m < 8; ++m) accB[m] = (f32x4){0.f, 0.f, 0.f, 0.f};

  for (int hk = 0; hk < 2; ++hk) {  // K=128 in two 64-halves (LDS budget)
    if (hk) __syncthreads();
    // Stage emb rows [i0-7, i0+137) x 64 k, fp32 -> bf16.
#pragma unroll
    for (int it = 0; it < 9; ++it) {
      int idx = t + (it << 8);       // 0..2303 float4 units (144 rows x 16)
      int row = idx >> 4;
      int k4 = (idx & 15) << 2;
      int v = i0 - 7 + row;
      float4 g = make_float4(0.f, 0.f, 0.f, 0.f);
      if (v >= 0 && v < NV) g = *(const float4*)&emb[v * 128 + (hk << 6) + k4];
      uint2 pk;
      pk.x = f2bf(g.x) | ((unsigned int)f2bf(g.y) << 16);
      pk.y = f2bf(g.z) | ((unsigned int)f2bf(g.w) << 16);
      *(uint2*)&Es[row * 72 + k4] = pk;
    }
    // Stage weight tiles transposed: Wt[n][k] = W1[(half)k][h0+n].
    {
      const int n = t & 63;
      const int kg = (t >> 6) << 4;  // 0,16,32,48
#pragma unroll
      for (int kk = 0; kk < 16; kk += 2) {
        int k = kg + kk;
        int rA = (hk << 6) + k;
        float a0 = W1[rA * 256 + h0 + n];
        float a1 = W1[(rA + 1) * 256 + h0 + n];
        *(unsigned int*)&WtA[n * 72 + k] = f2bf(a0) | ((unsigned int)f2bf(a1) << 16);
        float c0 = W1[(128 + rA) * 256 + h0 + n];
        float c1 = W1[(128 + rA + 1) * 256 + h0 + n];
        *(unsigned int*)&WtB[n * 72 + k] = f2bf(c0) | ((unsigned int)f2bf(c1) << 16);
      }
    }
    __syncthreads();
    const int kq = quad << 3;
#pragma unroll
    for (int kc = 0; kc < 2; ++kc) {
      const int kb = (kc << 5) + kq;
      short8 fA = *(const short8*)&WtA[((wv << 4) + l15) * 72 + kb];
      short8 fB = *(const short8*)&WtB[((wv << 4) + l15) * 72 + kb];
#pragma unroll
      for (int mf = 0; mf < 9; ++mf) {
        short8 a = *(const short8*)&Es[((mf << 4) + l15) * 72 + kb];
        accA[mf] = __builtin_amdgcn_mfma_f32_16x16x32_bf16(a, fA, accA[mf], 0, 0, 0);
      }
#pragma unroll
      for (int mf = 0; mf < 8; ++mf) {
        short8 a = *(const short8*)&Es[(8 + (mf << 4) + l15) * 72 + kb];
        accB[mf] = __builtin_amdgcn_mfma_f32_16x16x32_bf16(a, fB, accB[mf], 0, 0, 0);
      }
    }
  }
  __syncthreads();
  // Store C tiles to LDS (bf16). C/D frag: row = quad*4+reg, col = lane&15.
  const int hcol = (wv << 4) + l15;  // this wave's n-frag column
  const float b1v = b1[h0 + hcol];   // fold b1 into A-part only
#pragma unroll
  for (int mf = 0; mf < 9; ++mf) {
    int rb = (mf << 4) + (quad << 2);
#pragma unroll
    for (int rr = 0; rr < 4; ++rr) {
      int r = rb + rr;
      if (r < 135) CA[r * 72 + hcol] = f2bf(accA[mf][rr] + b1v);
    }
  }
#pragma unroll
  for (int mf = 0; mf < 8; ++mf) {
    int rb = (mf << 4) + (quad << 2);
#pragma unroll
    for (int rr = 0; rr < 4; ++rr)
      CB[(rb + rr) * 72 + hcol] = f2bf(accB[mf][rr]);
  }
  if (t < 64) W2s[t] = f2bf(W2[h0 + t]);
  __syncthreads();
  // Edge phase: thread t owns edges E = t + 256j (k = t&7, q = t>>3 + 32j).
  const int k = t & 7;
  const int qb = t >> 3;
  float part[4] = {0.f, 0.f, 0.f, 0.f};
#pragma unroll
  for (int g = 0; g < 8; ++g) {
    const int s = (g + (k << 1)) & 7;  // granule rotation: conflict-uniform banks
    ushort8 wvv = *(const ushort8*)&W2s[s << 3];
    float wf[8];
#pragma unroll
    for (int jj = 0; jj < 8; ++jj) wf[jj] = bf2f(wvv[jj]);
#pragma unroll
    for (int j = 0; j < 4; ++j) {
      const int q = qb + (j << 5);
      ushort8 a8 = *(const ushort8*)&CA[(7 + q - k) * 72 + (s << 3)];
      ushort8 b8 = *(const ushort8*)&CB[q * 72 + (s << 3)];
      float p = part[j];
#pragma unroll
      for (int jj = 0; jj < 8; ++jj) {
        float x = bf2f(a8[jj]) + bf2f(b8[jj]);
        float e2 = __expf(x + x);
        float th = 1.f - 2.f / (e2 + 1.f);  // tanh
        p = fmaf(th, wf[jj], p);
      }
      part[j] = p;
    }
  }
  const int ebase = (blockIdx.y << 10) + t;
#pragma unroll
  for (int j = 0; j < 4; ++j)
    g_part[blockIdx.x * NEDGE + ebase + (j << 8)] = part[j];
}

// K2b: sum 4 h-tile partials, softplus -> g_d; gold sum (k==0 edges).
__global__ __launch_bounds__(256) void k2_fin(const float* __restrict__ b2) {
  __shared__ float red[256];
  const int tid = blockIdx.x * 256 + threadIdx.x;  // 0..16383, 8 edges each
  const float b2v = b2[0];
  float d[8];
#pragma unroll
  for (int m = 0; m < 8; ++m) d[m] = b2v;
#pragma unroll
  for (int sx = 0; sx < 4; ++sx) {
    const float* p = &g_part[sx * NEDGE + (tid << 3)];
    float4 pa = *(const float4*)p;
    float4 pb = *(const float4*)(p + 4);
    d[0] += pa.x; d[1] += pa.y; d[2] += pa.z; d[3] += pa.w;
    d[4] += pb.x; d[5] += pb.y; d[6] += pb.z; d[7] += pb.w;
  }
#pragma unroll
  for (int m = 0; m < 8; ++m) {
    float tv = d[m];
    d[m] = fmaxf(tv, 0.f) + __logf(1.f + __expf(-fabsf(tv)));  // softplus
  }
  *(float4*)&g_d[tid << 3] = make_float4(d[0], d[1], d[2], d[3]);
  *(float4*)&g_d[(tid << 3) + 4] = make_float4(d[4], d[5], d[6], d[7]);
  red[threadIdx.x] = d[0];  // k==0 edge of node tid+1 -> gold path
  __syncthreads();
  for (int o = 128; o > 0; o >>= 1) {
    if (threadIdx.x < o) red[threadIdx.x] += red[threadIdx.x + o];
    __syncthreads();
  }
  if (threadIdx.x == 0) atomicAdd(&g_gold, red[0]);
}

// K3: 256 chunks of L=64 steps; 32 blocks x 64 threads, 8 chunks/block.
__global__ __launch_bounds__(64) void k3_chunks() {
  __shared__ float w[64][64];  // [step][chunk_local*8 + k]
  const int t = threadIdx.x;
  const int b = blockIdx.x;  // 0..31
  const float* __restrict__ src = &g_d[b << 12];
#pragma unroll
  for (int it = 0; it < 16; ++it) {
    const int q = (t + (it << 6)) << 2;
    const int cl = q >> 9;
    const int r = q & 511;
    const int s = r >> 3, k = r & 7;
    *(float4*)&w[s][(cl << 3) + k] = *(const float4*)&src[q];
  }
  __syncthreads();
  if (b == 0 && t == 0) {
    for (int s = 0; s < 7; ++s)
      for (int k = s + 1; k < 8; ++k) w[s][k] = 1e30f;
  }
  __syncthreads();
  const int g = t >> 3, j = t & 7;
  float P[8];
#pragma unroll
  for (int k = 0; k < 8; ++k) P[k] = (k == j) ? 0.f : NEG;
  for (int s = 0; s < 64; ++s) {
    const float* wp = &w[s][g << 3];
    float4 wa = *(const float4*)wp;
    float4 wb = *(const float4*)(wp + 4);
    float nv = lse8(P[0] - wa.x, P[1] - wa.y, P[2] - wa.z, P[3] - wa.w,
                    P[4] - wb.x, P[5] - wb.y, P[6] - wb.z, P[7] - wb.w);
#pragma unroll
    for (int k = 7; k > 0; --k) P[k] = P[k - 1];
    P[0] = nv;
  }
  const int c = (b << 3) + g;
  float* mp = &g_mats[(c << 6) + j];
#pragma unroll
  for (int k = 0; k < 8; ++k) mp[k << 3] = P[k];
}

// K4: 16 blocks, each combines 16 consecutive chunk matrices sequentially.
__global__ __launch_bounds__(64) void k4_comb() {
  __shared__ float Bm[64];
  const int l = threadIdx.x;
  const int r = blockIdx.x;
  const int i = l >> 3, j = l & 7;
  Bm[l] = g_mats[(r << 10) + l];
  __syncthreads();
  for (int tt = 1; tt < 16; ++tt) {
    const float* __restrict__ A = &g_mats[(((r << 4) + tt) << 6) + (i << 3)];
    float nv = lse8(A[0] + Bm[j], A[1] + Bm[8 + j], A[2] + Bm[16 + j],
                    A[3] + Bm[24 + j], A[4] + Bm[32 + j], A[5] + Bm[40 + j],
                    A[6] + Bm[48 + j], A[7] + Bm[56 + j]);
    __syncthreads();
    Bm[(i << 3) + j] = nv;
    __syncthreads();
  }
  g_mats2[(r << 6) + l] = Bm[l];
}

// K5: final combine of 16 matrices + gold + output.
__global__ __launch_bounds__(64) void k5_final(float* __restrict__ out) {
  __shared__ float Bm[64];
  const int t = threadIdx.x;
  Bm[t] = g_mats2[t];
  __syncthreads();
  const int i = t >> 3, j = t & 7;
  for (int tt = 1; tt < 16; ++tt) {
    const float* __restrict__ A = &g_mats2[(tt << 6) + (i << 3)];
    float nv = lse8(A[0] + Bm[j], A[1] + Bm[8 + j], A[2] + Bm[16 + j],
                    A[3] + Bm[24 + j], A[4] + Bm[32 + j], A[5] + Bm[40 + j],
                    A[6] + Bm[48 + j], A[7] + Bm[56 + j]);
    __syncthreads();
    Bm[(i << 3) + j] = nv;
    __syncthreads();
  }
  if (t == 0) out[0] = g_gold + Bm[0];
}

extern "C" void kernel_launch(void* const* d_in, const int* in_sizes, int n_in,
                              void* d_out, int out_size, void* d_ws, size_t ws_size,
                              hipStream_t stream) {
  const float* emb = (const float*)d_in[0];
  const float* W1 = (const float*)d_in[1];
  const float* b1 = (const float*)d_in[2];
  const float* W2 = (const float*)d_in[3];
  const float* b2 = (const float*)d_in[4];
  float* out = (float*)d_out;
  hipLaunchKernelGGL(k12_fused, dim3(4, 128), dim3(256), 0, stream, emb, W1, b1, W2);
  hipLaunchKernelGGL(k2_fin, dim3(64), dim3(256), 0, stream, b2);
  hipLaunchKernelGGL(k3_chunks, dim3(32), dim3(64), 0, stream);
  hipLaunchKernelGGL(k4_comb, dim3(16), dim3(64), 0, stream);
  hipLaunchKernelGGL(k5_final, dim3(1), dim3(64), 0, stream, out);
}

// Round 5
// 126.511 us; speedup vs baseline: 1.5863x; 1.1254x over previous
//
#include <hip/hip_runtime.h>
#include <math.h>

#define NNODES 16384
#define NV 16385
#define NEDGE 131072
#define NEG -1e30f
#define SCALE 2.8853900817779268f  // 2*log2(e): tanh(x) = 1 - 2/(exp2(SCALE*x)+1)

typedef __attribute__((ext_vector_type(8))) short short8;
typedef __attribute__((ext_vector_type(8))) unsigned short ushort8;
typedef __attribute__((ext_vector_type(4))) float f32x4;

// Scratch as static device globals (fully rewritten every launch).
__device__ float g_part[4 * NEDGE];  // per-h-tile partial edge sums
__device__ float g_mats[256 * 64];   // 256 chunk matrices (8x8, row-major)
__device__ float g_mats2[16 * 64];   // level-2 combined matrices
__device__ float g_gold;             // gold-path sum

__device__ __forceinline__ unsigned short f2bf(float x) {
  union { float f; unsigned int u; } c; c.f = x;
  unsigned int u = c.u;
  unsigned int r = (u + 0x7fffu + ((u >> 16) & 1u)) >> 16;  // RNE
  return (unsigned short)r;
}
__device__ __forceinline__ float bf2f(unsigned short u) {
  union { unsigned int u; float f; } c; c.u = ((unsigned int)u) << 16;
  return c.f;
}

__device__ __forceinline__ float lse8(float x0, float x1, float x2, float x3,
                                      float x4, float x5, float x6, float x7) {
  float m = fmaxf(fmaxf(fmaxf(x0, x1), fmaxf(x2, x3)),
                  fmaxf(fmaxf(x4, x5), fmaxf(x6, x7)));
  float s = __expf(x0 - m) + __expf(x1 - m) + __expf(x2 - m) + __expf(x3 - m) +
            __expf(x4 - m) + __expf(x5 - m) + __expf(x6 - m) + __expf(x7 - m);
  return m + __logf(s);
}

// Fused projection + edge kernel. Grid (4 h-tiles, 256 node-tiles of 64), 256 thr.
// Block (hx, vy): h in [hx*64, hx*64+64), nodes i in [i0+1, i0+64], i0 = vy*64.
// Phase 1 (MFMA): A[p][h] = emb[p]@W1_top (rows p = i0-7+r), B[i][h] = emb[i]@W1_bot.
// C tiles stored to LDS pre-scaled by 2*log2e (b1 folded into A).
// Phase 2: per-edge partial  sum_h tanh(.)*W2[h] = sum W2 - 2*sum W2*rcp(exp2(x)+1).
__global__ __launch_bounds__(256, 5) void k12_fused(const float* __restrict__ emb,
                                                    const float* __restrict__ W1,
                                                    const float* __restrict__ b1,
                                                    const float* __restrict__ W2) {
  __shared__ unsigned short lds[15072];        // 29.4 KB
  unsigned short* Es  = lds;                   // [80][72] emb tile (pitch 72)
  unsigned short* WtA = lds + 5760;            // [64][72]
  unsigned short* WtB = lds + 10368;           // [64][72]
  unsigned short* CA  = lds;                   // [80][72]  (aliases Es, phase 2)
  unsigned short* CB  = lds + 5760;            // [64][72]  (aliases WtA)
  unsigned short* W2s = lds + 14976;           // [64]  bf16(-2*W2)
  float* Wsum = (float*)(lds + 15040);         // [8]   per-granule sum of W2 (fp32)

  const int t = threadIdx.x;
  const int h0 = blockIdx.x << 6;
  const int i0 = blockIdx.y << 6;
  if (blockIdx.x == 0 && blockIdx.y == 0 && t == 0) g_gold = 0.f;
  const int wv = t >> 6, lane = t & 63;
  const int l15 = lane & 15, quad = lane >> 4;

  // W2 prep (region disjoint from staging; visible after first barrier).
  if (t < 64) W2s[t] = f2bf(-2.f * W2[h0 + t]);
  if (t < 8) {
    float s = 0.f;
#pragma unroll
    for (int jj = 0; jj < 8; ++jj) s += W2[h0 + (t << 3) + jj];
    Wsum[t] = s;
  }

  f32x4 accA[5], accB[4];
#pragma unroll
  for (int m = 0; m < 5; ++m) accA[m] = (f32x4){0.f, 0.f, 0.f, 0.f};
#pragma unroll
  for (int m = 0; m < 4; ++m) accB[m] = (f32x4){0.f, 0.f, 0.f, 0.f};

  for (int hk = 0; hk < 2; ++hk) {  // K=128 in two 64-halves
    if (hk) __syncthreads();        // protect Es/Wt from restage while in use
    // Stage emb rows [i0-7, i0+73) x 64 k -> bf16. 80 rows x 16 float4 = 1280.
#pragma unroll
    for (int it = 0; it < 5; ++it) {
      int idx = t + (it << 8);
      int row = idx >> 4;
      int k4 = (idx & 15) << 2;
      int v = i0 - 7 + row;
      float4 g = make_float4(0.f, 0.f, 0.f, 0.f);
      if (v >= 0 && v < NV) g = *(const float4*)&emb[v * 128 + (hk << 6) + k4];
      uint2 pk;
      pk.x = f2bf(g.x) | ((unsigned int)f2bf(g.y) << 16);
      pk.y = f2bf(g.z) | ((unsigned int)f2bf(g.w) << 16);
      *(uint2*)&Es[row * 72 + k4] = pk;
    }
    // Stage weight tiles transposed: Wt[n][k] = W1[.][h0+n].
    {
      const int n = t & 63;
      const int kg = (t >> 6) << 4;  // 0,16,32,48
#pragma unroll
      for (int kk = 0; kk < 16; kk += 2) {
        int k = (hk << 6) + kg + kk;
        float a0 = W1[k * 256 + h0 + n];
        float a1 = W1[(k + 1) * 256 + h0 + n];
        *(unsigned int*)&WtA[n * 72 + kg + kk] = f2bf(a0) | ((unsigned int)f2bf(a1) << 16);
        float c0 = W1[(128 + k) * 256 + h0 + n];
        float c1 = W1[(128 + k + 1) * 256 + h0 + n];
        *(unsigned int*)&WtB[n * 72 + kg + kk] = f2bf(c0) | ((unsigned int)f2bf(c1) << 16);
      }
    }
    __syncthreads();
    const int kq = quad << 3;
#pragma unroll
    for (int kc = 0; kc < 2; ++kc) {
      const int kb = (kc << 5) + kq;
      short8 fA = *(const short8*)&WtA[((wv << 4) + l15) * 72 + kb];
      short8 fB = *(const short8*)&WtB[((wv << 4) + l15) * 72 + kb];
#pragma unroll
      for (int mf = 0; mf < 5; ++mf) {
        short8 a = *(const short8*)&Es[((mf << 4) + l15) * 72 + kb];
        accA[mf] = __builtin_amdgcn_mfma_f32_16x16x32_bf16(a, fA, accA[mf], 0, 0, 0);
      }
#pragma unroll
      for (int mf = 0; mf < 4; ++mf) {
        short8 a = *(const short8*)&Es[(8 + (mf << 4) + l15) * 72 + kb];
        accB[mf] = __builtin_amdgcn_mfma_f32_16x16x32_bf16(a, fB, accB[mf], 0, 0, 0);
      }
    }
  }
  __syncthreads();  // all MFMA reads done before aliasing C over Es/WtA
  // Store C tiles (bf16, pre-scaled). C/D frag: row = quad*4+reg, col = lane&15.
  const int hcol = (wv << 4) + l15;
  const float b1s = b1[h0 + hcol];
#pragma unroll
  for (int mf = 0; mf < 5; ++mf) {
    int rb = (mf << 4) + (quad << 2);
#pragma unroll
    for (int rr = 0; rr < 4; ++rr)
      CA[(rb + rr) * 72 + hcol] = f2bf((accA[mf][rr] + b1s) * SCALE);
  }
#pragma unroll
  for (int mf = 0; mf < 4; ++mf) {
    int rb = (mf << 4) + (quad << 2);
#pragma unroll
    for (int rr = 0; rr < 4; ++rr)
      CB[(rb + rr) * 72 + hcol] = f2bf(accB[mf][rr] * SCALE);
  }
  __syncthreads();
  // Edge phase: thread t -> k = t&7, qb = t>>3; edges q = qb, qb+32.
  const int k = t & 7;
  const int qb = t >> 3;
  float part[2] = {0.f, 0.f};
#pragma unroll
  for (int g = 0; g < 8; ++g) {
    const int s = (g + (k << 1)) & 7;  // granule rotation: conflict-uniform banks
    ushort8 wv8 = *(const ushort8*)&W2s[s << 3];
    float m2w[8];
#pragma unroll
    for (int jj = 0; jj < 8; ++jj) m2w[jj] = bf2f(wv8[jj]);
    const float ws = Wsum[s];
#pragma unroll
    for (int j = 0; j < 2; ++j) {
      const int q = qb + (j << 5);
      ushort8 a8 = *(const ushort8*)&CA[(7 + q - k) * 72 + (s << 3)];
      ushort8 b8 = *(const ushort8*)&CB[q * 72 + (s << 3)];
      float p = part[j];
#pragma unroll
      for (int jj = 0; jj < 8; ++jj) {
        float x = bf2f(a8[jj]) + bf2f(b8[jj]);           // 2*log2e*(A+B+b1)
        float e = __builtin_amdgcn_exp2f(x);
        float r = __builtin_amdgcn_rcpf(e + 1.f);
        p = fmaf(r, m2w[jj], p);                          // p += -2*W2*r
      }
      part[j] = p + ws;                                   // + sum W2 (tanh fold)
    }
  }
  const int ebase = blockIdx.x * NEDGE + (blockIdx.y << 9) + t;
  g_part[ebase] = part[0];
  g_part[ebase + 256] = part[1];
}

// K23: fused partial-sum + softplus + gold + chunk recurrence.
// 32 blocks x 256 thr; block b owns edges [b*4096, b*4096+4096) = chunks 8b..8b+7.
__global__ __launch_bounds__(256) void k23_chunks(const float* __restrict__ b2) {
  __shared__ float w[64][64];   // [step][chunk_local*8 + k]
  __shared__ float red[256];
  const int t = threadIdx.x;
  const int b = blockIdx.x;
  const float b2v = b2[0];
  float gold = 0.f;
#pragma unroll
  for (int it = 0; it < 4; ++it) {
    const int e4 = t + (it << 8);          // float4 unit within block (0..1023)
    const int gidx = (b << 10) + e4;
    float4 s0 = *(const float4*)&g_part[gidx << 2];
    float4 s1 = *(const float4*)&g_part[NEDGE + (gidx << 2)];
    float4 s2 = *(const float4*)&g_part[2 * NEDGE + (gidx << 2)];
    float4 s3 = *(const float4*)&g_part[3 * NEDGE + (gidx << 2)];
    float d0 = s0.x + s1.x + s2.x + s3.x + b2v;
    float d1 = s0.y + s1.y + s2.y + s3.y + b2v;
    float d2 = s0.z + s1.z + s2.z + s3.z + b2v;
    float d3 = s0.w + s1.w + s2.w + s3.w + b2v;
    d0 = fmaxf(d0, 0.f) + log1pf(__expf(-fabsf(d0)));
    d1 = fmaxf(d1, 0.f) + log1pf(__expf(-fabsf(d1)));
    d2 = fmaxf(d2, 0.f) + log1pf(__expf(-fabsf(d2)));
    d3 = fmaxf(d3, 0.f) + log1pf(__expf(-fabsf(d3)));
    const int q = e4 << 2;                 // block-local edge id
    const int cl = q >> 9, r = q & 511;
    const int s = r >> 3, kk = r & 7;
    *(float4*)&w[s][(cl << 3) + kk] = make_float4(d0, d1, d2, d3);
    if ((t & 1) == 0) gold += d0;          // k==0 edges (gold path)
  }
  red[t] = gold;
  __syncthreads();
  if (b == 0 && t == 0) {
    // node i = s+1 has valid preds k <= s only: poison invalid d with +1e30
    for (int s = 0; s < 7; ++s)
      for (int kk = s + 1; kk < 8; ++kk) w[s][kk] = 1e30f;
  }
  for (int o = 128; o > 0; o >>= 1) {
    __syncthreads();
    if (t < o) red[t] += red[t + o];
  }
  __syncthreads();
  if (t == 0) atomicAdd(&g_gold, red[0]);
  if (t < 64) {
    const int g = t >> 3, j = t & 7;
    float P[8];
#pragma unroll
    for (int kk = 0; kk < 8; ++kk) P[kk] = (kk == j) ? 0.f : NEG;
    for (int s = 0; s < 64; ++s) {
      const float* wp = &w[s][g << 3];
      float4 wa = *(const float4*)wp;
      float4 wb = *(const float4*)(wp + 4);
      float nv = lse8(P[0] - wa.x, P[1] - wa.y, P[2] - wa.z, P[3] - wa.w,
                      P[4] - wb.x, P[5] - wb.y, P[6] - wb.z, P[7] - wb.w);
#pragma unroll
      for (int kk = 7; kk > 0; --kk) P[kk] = P[kk - 1];
      P[0] = nv;
    }
    const int c = (b << 3) + g;
    float* mp = &g_mats[(c << 6) + j];
#pragma unroll
    for (int kk = 0; kk < 8; ++kk) mp[kk << 3] = P[kk];
  }
}

// K4: 16 blocks, each combines 16 consecutive chunk matrices sequentially.
__global__ __launch_bounds__(64) void k4_comb() {
  __shared__ float Bm[64];
  const int l = threadIdx.x;
  const int r = blockIdx.x;
  const int i = l >> 3, j = l & 7;
  Bm[l] = g_mats[(r << 10) + l];
  __syncthreads();
  for (int tt = 1; tt < 16; ++tt) {
    const float* __restrict__ A = &g_mats[(((r << 4) + tt) << 6) + (i << 3)];
    float nv = lse8(A[0] + Bm[j], A[1] + Bm[8 + j], A[2] + Bm[16 + j],
                    A[3] + Bm[24 + j], A[4] + Bm[32 + j], A[5] + Bm[40 + j],
                    A[6] + Bm[48 + j], A[7] + Bm[56 + j]);
    __syncthreads();
    Bm[(i << 3) + j] = nv;
    __syncthreads();
  }
  g_mats2[(r << 6) + l] = Bm[l];
}

// K5: final combine of 16 matrices + gold + output.
__global__ __launch_bounds__(64) void k5_final(float* __restrict__ out) {
  __shared__ float Bm[64];
  const int t = threadIdx.x;
  Bm[t] = g_mats2[t];
  __syncthreads();
  const int i = t >> 3, j = t & 7;
  for (int tt = 1; tt < 16; ++tt) {
    const float* __restrict__ A = &g_mats2[(tt << 6) + (i << 3)];
    float nv = lse8(A[0] + Bm[j], A[1] + Bm[8 + j], A[2] + Bm[16 + j],
                    A[3] + Bm[24 + j], A[4] + Bm[32 + j], A[5] + Bm[40 + j],
                    A[6] + Bm[48 + j], A[7] + Bm[56 + j]);
    __syncthreads();
    Bm[(i << 3) + j] = nv;
    __syncthreads();
  }
  if (t == 0) out[0] = g_gold + Bm[0];
}

extern "C" void kernel_launch(void* const* d_in, const int* in_sizes, int n_in,
                              void* d_out, int out_size, void* d_ws, size_t ws_size,
                              hipStream_t stream) {
  const float* emb = (const float*)d_in[0];
  const float* W1 = (const float*)d_in[1];
  const float* b1 = (const float*)d_in[2];
  const float* W2 = (const float*)d_in[3];
  const float* b2 = (const float*)d_in[4];
  float* out = (float*)d_out;
  hipLaunchKernelGGL(k12_fused, dim3(4, 256), dim3(256), 0, stream, emb, W1, b1, W2);
  hipLaunchKernelGGL(k23_chunks, dim3(32), dim3(256), 0, stream, b2);
  hipLaunchKernelGGL(k4_comb, dim3(16), dim3(64), 0, stream);
  hipLaunchKernelGGL(k5_final, dim3(1), dim3(64), 0, stream, out);
}